// Round 1
// baseline (821.572 us; speedup 1.0000x reference)
//
#include <hip/hip_runtime.h>

// VectorQuantizer on MI355X.
// Phase A (vq_setup): np-pairwise-order sum(e^2) per code -> senp[], ekkh[]=0.5*senp, zero loss.
// Phase B (vq_main): f16 MFMA approx scores t = x.e - 0.5*||e||^2, per-row running max +
//                    margin-filtered candidate list, then exact rescore (double dot, numpy-order
//                    fp32 quantization, first-index tie-break), write quantized + loss partials.
// Phase C (vq_fin):  loss = 1.25 * S / 8388608 -> out[8388608].

#define D        256
#define KCODES   8192
#define NROWS    32768
#define MB       128      // rows per block
#define NT       128      // codes per K-iter
#define THREADS  512      // 8 waves: 4 row-groups x 2 col-groups
#define CAP      32       // candidate slots per row
#define MARGIN   0.03f    // filter margin on t-scale (err bound ~7e-3, RMS ~2e-4)
#define LDA      264      // D + 8 halves padding (16B) to break 512B-stride conflicts
#define NOUT     8388608

typedef _Float16 h8_t __attribute__((ext_vector_type(8)));
typedef _Float16 h4_t __attribute__((ext_vector_type(4)));
typedef float    f4_t __attribute__((ext_vector_type(4)));

__device__ __forceinline__ float clipf(float v) { return fminf(1.0f, fmaxf(-1.0f, v)); }

// ordered-uint encoding for float atomicMax (handles negatives)
__device__ __forceinline__ unsigned int fkey(float f) {
  unsigned int b = __float_as_uint(f);
  return (b & 0x80000000u) ? ~b : (b | 0x80000000u);
}
__device__ __forceinline__ float funkey(unsigned int u) {
  return __uint_as_float((u & 0x80000000u) ? (u & 0x7fffffffu) : ~u);
}

// max across each 16-lane DPP row via row_ror (VALU pipe, no LDS traffic)
#define DPP_ROR(x, n) __int_as_float(__builtin_amdgcn_update_dpp( \
    0, __float_as_int(x), 0x120 + (n), 0xF, 0xF, true))
__device__ __forceinline__ float maxrow16(float x) {
  x = fmaxf(x, DPP_ROR(x, 1));
  x = fmaxf(x, DPP_ROR(x, 2));
  x = fmaxf(x, DPP_ROR(x, 4));
  x = fmaxf(x, DPP_ROR(x, 8));
  return x;
}

// ---------------- setup: per-code sum(e^2) in numpy pairwise order ----------------
__global__ void vq_setup(const float* __restrict__ emb, float* __restrict__ senp,
                         float* __restrict__ ekkh, float* __restrict__ lossacc) {
  const int wid  = threadIdx.x >> 6;
  const int lane = threadIdx.x & 63;
  const int k    = blockIdx.x * 4 + wid;
  if (blockIdx.x == 0 && threadIdx.x == 0) lossacc[0] = 0.0f;
  float r = 0.0f;
  if (lane < 16) {
    const int hf = lane >> 3, jj = lane & 7;
    const float* base = emb + (size_t)k * D + hf * 128 + jj;
    float v = base[0];
    r = v * v;
    #pragma unroll
    for (int m = 1; m < 16; ++m) { v = base[8 * m]; r += v * v; }
  }
  float p[16];
  #pragma unroll
  for (int j = 0; j < 16; ++j) p[j] = __shfl(r, j, 64);
  float h0 = ((p[0] + p[1]) + (p[2] + p[3])) + ((p[4] + p[5]) + (p[6] + p[7]));
  float h1 = ((p[8] + p[9]) + (p[10] + p[11])) + ((p[12] + p[13]) + (p[14] + p[15]));
  float s = h0 + h1;
  if (lane == 0) { senp[k] = s; ekkh[k] = 0.5f * s; }
}

// ---------------- main kernel ----------------
__global__ void __launch_bounds__(THREADS)
vq_main(const float* __restrict__ xin, const float* __restrict__ emb,
        const float* __restrict__ senp, const float* __restrict__ ekkh,
        float* __restrict__ out, float* __restrict__ lossacc) {
  __shared__ _Float16 As[MB][LDA];           // 67584 B
  __shared__ _Float16 Bs[NT][LDA];           // 67584 B
  __shared__ unsigned int rowmaxU[MB];       //   512 B
  __shared__ int cnt[MB];                    //   512 B
  __shared__ unsigned short cand[MB][CAP];   //  8192 B
  __shared__ float xrow[8][D];               //  8192 B
  __shared__ float rpart[8][16];             //   512 B   total = 153088 B

  const int tid  = threadIdx.x;
  const int lane = tid & 63;
  const int wid  = tid >> 6;
  const int l15  = lane & 15;
  const int quad = lane >> 4;
  const int mw   = wid >> 1;   // 0..3
  const int nw   = wid & 1;    // 0..1
  const int rowbase = mw * 32;
  const int r0 = blockIdx.x * MB;

  for (int i = tid; i < MB; i += THREADS) { rowmaxU[i] = fkey(-INFINITY); cnt[i] = 0; }

  // stage A: clip + fp16 convert, 128x256
  #pragma unroll
  for (int rnd = 0; rnd < 16; ++rnd) {
    int e = rnd * (THREADS * 4) + tid * 4;
    int row = e >> 8, col = e & 255;
    f4_t v = *(const f4_t*)(xin + (size_t)(r0 + row) * D + col);
    h4_t h;
    h[0] = (_Float16)clipf(v[0]); h[1] = (_Float16)clipf(v[1]);
    h[2] = (_Float16)clipf(v[2]); h[3] = (_Float16)clipf(v[3]);
    *(h4_t*)&As[row][col] = h;
  }

  for (int c0 = 0; c0 < KCODES; c0 += NT) {
    __syncthreads();   // prior iter's Bs reads complete
    // stage B: fp32 -> fp16, 128 codes x 256
    #pragma unroll
    for (int rnd = 0; rnd < 16; ++rnd) {
      int e = rnd * (THREADS * 4) + tid * 4;
      int code = e >> 8, col = e & 255;
      f4_t v = *(const f4_t*)(emb + (size_t)(c0 + code) * D + col);
      h4_t h;
      h[0] = (_Float16)v[0]; h[1] = (_Float16)v[1];
      h[2] = (_Float16)v[2]; h[3] = (_Float16)v[3];
      *(h4_t*)&Bs[code][col] = h;
    }
    __syncthreads();

    f4_t acc[2][4];
    #pragma unroll
    for (int a = 0; a < 2; ++a)
      #pragma unroll
      for (int b = 0; b < 4; ++b) { f4_t z = {0.f, 0.f, 0.f, 0.f}; acc[a][b] = z; }

    #pragma unroll
    for (int kc = 0; kc < 8; ++kc) {
      const int ko = kc * 32 + quad * 8;
      h8_t a0 = *(const h8_t*)&As[rowbase      + l15][ko];
      h8_t a1 = *(const h8_t*)&As[rowbase + 16 + l15][ko];
      h8_t b0 = *(const h8_t*)&Bs[nw * 64      + l15][ko];
      h8_t b1 = *(const h8_t*)&Bs[nw * 64 + 16 + l15][ko];
      h8_t b2 = *(const h8_t*)&Bs[nw * 64 + 32 + l15][ko];
      h8_t b3 = *(const h8_t*)&Bs[nw * 64 + 48 + l15][ko];
      acc[0][0] = __builtin_amdgcn_mfma_f32_16x16x32_f16(a0, b0, acc[0][0], 0, 0, 0);
      acc[0][1] = __builtin_amdgcn_mfma_f32_16x16x32_f16(a0, b1, acc[0][1], 0, 0, 0);
      acc[0][2] = __builtin_amdgcn_mfma_f32_16x16x32_f16(a0, b2, acc[0][2], 0, 0, 0);
      acc[0][3] = __builtin_amdgcn_mfma_f32_16x16x32_f16(a0, b3, acc[0][3], 0, 0, 0);
      acc[1][0] = __builtin_amdgcn_mfma_f32_16x16x32_f16(a1, b0, acc[1][0], 0, 0, 0);
      acc[1][1] = __builtin_amdgcn_mfma_f32_16x16x32_f16(a1, b1, acc[1][1], 0, 0, 0);
      acc[1][2] = __builtin_amdgcn_mfma_f32_16x16x32_f16(a1, b2, acc[1][2], 0, 0, 0);
      acc[1][3] = __builtin_amdgcn_mfma_f32_16x16x32_f16(a1, b3, acc[1][3], 0, 0, 0);
    }

    float ekk[4]; int codeAt[4];
    #pragma unroll
    for (int ns = 0; ns < 4; ++ns) {
      codeAt[ns] = c0 + nw * 64 + ns * 16 + l15;
      ekk[ns] = ekkh[codeAt[ns]];
    }

    // running per-row max (DPP reduce over the 16 lanes covering all cols of a row)
    #pragma unroll
    for (int ms = 0; ms < 2; ++ms) {
      #pragma unroll
      for (int r = 0; r < 4; ++r) {
        int row = rowbase + ms * 16 + quad * 4 + r;
        float t0 = acc[ms][0][r] - ekk[0];
        float t1 = acc[ms][1][r] - ekk[1];
        float t2 = acc[ms][2][r] - ekk[2];
        float t3 = acc[ms][3][r] - ekk[3];
        float tm = fmaxf(fmaxf(t0, t1), fmaxf(t2, t3));
        tm = maxrow16(tm);
        if (l15 == 0) atomicMax(&rowmaxU[row], fkey(tm));
      }
    }

    // margin-filtered append (cutoff is monotone: any stale value still captures the winner)
    #pragma unroll
    for (int ms = 0; ms < 2; ++ms) {
      #pragma unroll
      for (int r = 0; r < 4; ++r) {
        int row = rowbase + ms * 16 + quad * 4 + r;
        float cut = funkey(rowmaxU[row]) - MARGIN;
        #pragma unroll
        for (int ns = 0; ns < 4; ++ns) {
          float t = acc[ms][ns][r] - ekk[ns];
          if (t >= cut) {
            int s = atomicAdd(&cnt[row], 1);
            if (s < CAP) cand[row][s] = (unsigned short)codeAt[ns];
          }
        }
      }
    }
  }

  __syncthreads();

  // ---------------- exact rescore + output + loss ----------------
  const int lane4 = lane * 4;
  for (int rr = 0; rr < 16; ++rr) {
    const int row = wid + rr * 8;
    f4_t xv = *(const f4_t*)(xin + (size_t)(r0 + row) * D + lane4);
    xv[0] = clipf(xv[0]); xv[1] = clipf(xv[1]); xv[2] = clipf(xv[2]); xv[3] = clipf(xv[3]);
    *(f4_t*)&xrow[wid][lane4] = xv;
    __builtin_amdgcn_wave_barrier();
    if (lane < 16) {   // numpy pairwise sum of x^2 (exact order)
      const int hf = lane >> 3, jj = lane & 7;
      const float* base = &xrow[wid][hf * 128 + jj];
      float v = base[0];
      float rs = v * v;
      #pragma unroll
      for (int m = 1; m < 16; ++m) { v = base[8 * m]; rs += v * v; }
      rpart[wid][lane] = rs;
    }
    __builtin_amdgcn_wave_barrier();
    float p[16];
    #pragma unroll
    for (int j = 0; j < 16; ++j) p[j] = rpart[wid][j];
    float h0 = ((p[0] + p[1]) + (p[2] + p[3])) + ((p[4] + p[5]) + (p[6] + p[7]));
    float h1 = ((p[8] + p[9]) + (p[10] + p[11])) + ((p[12] + p[13]) + (p[14] + p[15]));
    float sx = h0 + h1;

    int nc = cnt[row]; nc = nc > CAP ? CAP : nc;
    float bd = INFINITY; int bk = 0;
    for (int ci = 0; ci < nc; ++ci) {
      int k = cand[row][ci];
      f4_t ev = *(const f4_t*)(emb + (size_t)k * D + lane4);
      double dd = (double)xv[0] * (double)ev[0] + (double)xv[1] * (double)ev[1]
                + (double)xv[2] * (double)ev[2] + (double)xv[3] * (double)ev[3];
      #pragma unroll
      for (int off = 1; off < 64; off <<= 1) dd += __shfl_xor(dd, off, 64);
      float T1 = sx + senp[k];          // fp32, numpy op order
      float T2 = (float)(2.0 * dd);     // fp32-rounded 2*dot
      float d  = T1 - T2;               // final fp32 quantization like numpy
      if (d < bd || (d == bd && k < bk)) { bd = d; bk = k; }
    }

    f4_t ev = *(const f4_t*)(emb + (size_t)bk * D + lane4);
    *(f4_t*)(out + (size_t)(r0 + row) * D + lane4) = ev;
    float ls = 0.0f;
    #pragma unroll
    for (int i = 0; i < 4; ++i) { float df = ev[i] - xv[i]; ls += df * df; }
    #pragma unroll
    for (int off = 1; off < 64; off <<= 1) ls += __shfl_xor(ls, off, 64);
    if (lane == 0) atomicAdd(lossacc, ls);
  }
}

// ---------------- finalize loss ----------------
__global__ void vq_fin(const float* __restrict__ lossacc, float* __restrict__ out) {
  out[NOUT] = 1.25f * lossacc[0] / 8388608.0f;
}

extern "C" void kernel_launch(void* const* d_in, const int* in_sizes, int n_in,
                              void* d_out, int out_size, void* d_ws, size_t ws_size,
                              hipStream_t stream) {
  const float* xin = (const float*)d_in[0];
  const float* emb = (const float*)d_in[1];
  float* out = (float*)d_out;
  float* ws  = (float*)d_ws;
  float* lossacc = ws;              // 1 float
  float* senp    = ws + 256;        // 8192 floats: numpy-order sum(e^2)
  float* ekkh    = ws + 256 + KCODES; // 8192 floats: 0.5*sum(e^2)
  vq_setup<<<dim3(KCODES / 4), dim3(256), 0, stream>>>(emb, senp, ekkh, lossacc);
  vq_main<<<dim3(NROWS / MB), dim3(THREADS), 0, stream>>>(xin, emb, senp, ekkh, out, lossacc);
  vq_fin<<<dim3(1), dim3(1), 0, stream>>>(lossacc, out);
}

// Round 2
// 376.998 us; speedup vs baseline: 2.1792x; 2.1792x over previous
//
#include <hip/hip_runtime.h>

// VectorQuantizer on MI355X — R2: f16 codebook pre-pack (fragment-major, DMA-linear),
// global_load_lds double-buffered K-loop (1 barrier/iter), A-fragments in registers,
// register-gated margin filter, exact rescore (numpy-order fp32), block-local loss.

#define D        256
#define KCODES   8192
#define NROWS    32768
#define MB       128      // rows per block
#define NT       64       // codes per tile
#define NTILES   (KCODES / NT)   // 128
#define THREADS  512
#define CAP      32
#define MARGIN   0.03f    // filter margin (f16 score err RMS ~1e-3)
#define BIAS     32.0f    // positive-bias so int-compare == float-compare for rowmax
#define NOUT     8388608

typedef _Float16 h8_t __attribute__((ext_vector_type(8)));
typedef float    f4_t __attribute__((ext_vector_type(4)));

__device__ __forceinline__ float clipf(float v) { return fminf(1.0f, fmaxf(-1.0f, v)); }

// max across each 16-lane group via row_ror DPP
#define DPP_ROR(x, n) __int_as_float(__builtin_amdgcn_update_dpp( \
    0, __float_as_int(x), 0x120 + (n), 0xF, 0xF, true))
__device__ __forceinline__ float maxrow16(float x) {
  x = fmaxf(x, DPP_ROR(x, 1));
  x = fmaxf(x, DPP_ROR(x, 2));
  x = fmaxf(x, DPP_ROR(x, 4));
  x = fmaxf(x, DPP_ROR(x, 8));
  return x;
}

__device__ __forceinline__ void gld_lds16(const void* g, void* l) {
  __builtin_amdgcn_global_load_lds(
      (const __attribute__((address_space(1))) unsigned int*)g,
      (__attribute__((address_space(3))) unsigned int*)l, 16, 0, 0);
}

// ---------------- setup: per-code sum(e^2) in numpy pairwise order ----------------
__global__ void vq_setup(const float* __restrict__ emb, float* __restrict__ senp,
                         float* __restrict__ ekkb, float* __restrict__ lossacc) {
  const int wid  = threadIdx.x >> 6;
  const int lane = threadIdx.x & 63;
  const int k    = blockIdx.x * 4 + wid;
  if (blockIdx.x == 0 && threadIdx.x == 0) lossacc[0] = 0.0f;
  float r = 0.0f;
  if (lane < 16) {
    const int hf = lane >> 3, jj = lane & 7;
    const float* base = emb + (size_t)k * D + hf * 128 + jj;
    float v = base[0];
    r = v * v;
    #pragma unroll
    for (int m = 1; m < 16; ++m) { v = base[8 * m]; r += v * v; }
  }
  float p[16];
  #pragma unroll
  for (int j = 0; j < 16; ++j) p[j] = __shfl(r, j, 64);
  float h0 = ((p[0] + p[1]) + (p[2] + p[3])) + ((p[4] + p[5]) + (p[6] + p[7]));
  float h1 = ((p[8] + p[9]) + (p[10] + p[11])) + ((p[12] + p[13]) + (p[14] + p[15]));
  float s = h0 + h1;
  if (lane == 0) { senp[k] = s; ekkb[k] = 0.5f * s - BIAS; }
}

// ---------------- pack: f16 codebook, fragment-major DMA-linear order ----------------
// tile t (64 codes): 16B chunk c in [0,2048): kc=c>>8, g=(c>>6)&3, lane=c&63;
// content = emb16[t*64 + g*16 + (lane&15)][kc*32 + (lane>>4)*8 .. +8]
__global__ void vq_pack(const float* __restrict__ emb, _Float16* __restrict__ femb) {
  const int t = blockIdx.x;
  #pragma unroll
  for (int j = 0; j < 8; ++j) {
    int c = j * 256 + threadIdx.x;
    int kc = c >> 8, g = (c >> 6) & 3, ln = c & 63;
    int code = t * 64 + g * 16 + (ln & 15);
    int k0 = kc * 32 + (ln >> 4) * 8;
    const float* sp = emb + (size_t)code * D + k0;
    f4_t v0 = *(const f4_t*)sp, v1 = *(const f4_t*)(sp + 4);
    h8_t h;
    h[0] = (_Float16)v0[0]; h[1] = (_Float16)v0[1];
    h[2] = (_Float16)v0[2]; h[3] = (_Float16)v0[3];
    h[4] = (_Float16)v1[0]; h[5] = (_Float16)v1[1];
    h[6] = (_Float16)v1[2]; h[7] = (_Float16)v1[3];
    *(h8_t*)(femb + (size_t)t * 16384 + (size_t)c * 8) = h;
  }
}

// ---------------- main ----------------
__global__ void __launch_bounds__(THREADS, 2)
vq_main(const float* __restrict__ xin, const _Float16* __restrict__ femb,
        const float* __restrict__ emb, const float* __restrict__ senp,
        const float* __restrict__ ekkb, float* __restrict__ out,
        float* __restrict__ lossacc) {
  __shared__ alignas(16) char Bs0[32768];
  __shared__ alignas(16) char Bs1[32768];
  __shared__ int rowmaxI[MB];
  __shared__ int cnt[MB];
  __shared__ unsigned short cand[MB][CAP];
  __shared__ float blksum;

  const int tid  = threadIdx.x;
  const int lane = tid & 63;
  const int wid  = tid >> 6;
  const int l15  = lane & 15;
  const int quad = lane >> 4;
  const int mw   = wid >> 2;   // 0..1 : 64-row group
  const int ng   = wid & 3;    // 0..3 : 16-col group
  const int r0   = blockIdx.x * MB;

  for (int i = tid; i < MB; i += THREADS) { rowmaxI[i] = 0; cnt[i] = 0; }
  if (tid == 0) blksum = 0.0f;

  // ---- stage x-tile (clipped f16, fragment order) into Bs0 (rows 0..63) / Bs1 (64..127)
  #pragma unroll
  for (int j = 0; j < 8; ++j) {
    int c = j * THREADS + tid;            // 0..4095
    int half = c >> 11;
    int c2 = c & 2047;
    int kc = c2 >> 8, g = (c2 >> 6) & 3, ln = c2 & 63;
    int row = half * 64 + g * 16 + (ln & 15);
    int k0 = kc * 32 + (ln >> 4) * 8;
    const float* ap = xin + (size_t)(r0 + row) * D + k0;
    f4_t v0 = *(const f4_t*)ap, v1 = *(const f4_t*)(ap + 4);
    h8_t h;
    h[0] = (_Float16)clipf(v0[0]); h[1] = (_Float16)clipf(v0[1]);
    h[2] = (_Float16)clipf(v0[2]); h[3] = (_Float16)clipf(v0[3]);
    h[4] = (_Float16)clipf(v1[0]); h[5] = (_Float16)clipf(v1[1]);
    h[6] = (_Float16)clipf(v1[2]); h[7] = (_Float16)clipf(v1[3]);
    *(h8_t*)((half ? Bs1 : Bs0) + (size_t)c2 * 16) = h;
  }
  __syncthreads();

  // ---- A fragments -> registers (whole K-loop invariant), 128 VGPRs
  h8_t afrag[4][8];
  {
    const char* abase = mw ? Bs1 : Bs0;
    #pragma unroll
    for (int ms = 0; ms < 4; ++ms)
      #pragma unroll
      for (int kc = 0; kc < 8; ++kc)
        afrag[ms][kc] = *(const h8_t*)(abase + (kc * 4 + ms) * 1024 + lane * 16);
  }
  __syncthreads();   // reads done before DMA overwrites Bs0

  const char* gth = (const char*)femb + (size_t)(wid * 1024 + lane * 16);
  #pragma unroll
  for (int q = 0; q < 4; ++q)   // prefetch tile 0 -> Bs0
    gld_lds16(gth + q * 8192, Bs0 + (q * 8 + wid) * 1024);

  float Lbm[4][4];
  #pragma unroll
  for (int a = 0; a < 4; ++a)
    #pragma unroll
    for (int b = 0; b < 4; ++b) Lbm[a][b] = -1e30f;

  const int mycol = ng * 16 + l15;

  for (int t = 0; t < NTILES; ++t) {
    char* cur = (t & 1) ? Bs1 : Bs0;
    char* nxt = (t & 1) ? Bs0 : Bs1;
    __syncthreads();            // DMA(t) drained; prior reads of nxt finished
    if (t + 1 < NTILES) {
      const char* g2 = gth + (size_t)(t + 1) * 32768;
      #pragma unroll
      for (int q = 0; q < 4; ++q)
        gld_lds16(g2 + q * 8192, nxt + (q * 8 + wid) * 1024);
    }
    const int c0 = t * NT;
    float negekk = -ekkb[c0 + mycol];
    f4_t acc[4];
    #pragma unroll
    for (int ms = 0; ms < 4; ++ms) {
      f4_t z = {negekk, negekk, negekk, negekk};
      acc[ms] = z;
    }
    #pragma unroll
    for (int kc = 0; kc < 8; ++kc) {
      h8_t b = *(const h8_t*)(cur + (kc * 4 + ng) * 1024 + lane * 16);
      #pragma unroll
      for (int ms = 0; ms < 4; ++ms)
        acc[ms] = __builtin_amdgcn_mfma_f32_16x16x32_f16(afrag[ms][kc], b, acc[ms], 0, 0, 0);
    }
    // margin filter, register-gated (Lbm <= global rowmax - MARGIN, monotone)
    #pragma unroll
    for (int ms = 0; ms < 4; ++ms) {
      #pragma unroll
      for (int r = 0; r < 4; ++r) {
        float t0 = acc[ms][r];
        if (__any(t0 > Lbm[ms][r])) {
          int row = mw * 64 + ms * 16 + quad * 4 + r;
          float mm = maxrow16(t0);
          if (l15 == 0) atomicMax(&rowmaxI[row], __float_as_int(mm));
          float cut = __int_as_float(rowmaxI[row]) - MARGIN;
          Lbm[ms][r] = cut;
          if (t0 >= cut) {
            int s = atomicAdd(&cnt[row], 1);
            if (s < CAP) cand[row][s] = (unsigned short)(c0 + mycol);
          }
        }
      }
    }
  }
  __syncthreads();

  // ---------------- exact rescore + output + loss (scratch over Bs0) ----------------
  float* xrow  = (float*)Bs0;           // 8 waves x 256 floats = 8 KB
  float* rpart = (float*)(Bs0 + 8192);  // 8 waves x 16 floats
  const int lane4 = lane * 4;
  for (int rr = 0; rr < 16; ++rr) {
    const int row = wid + rr * 8;
    f4_t xv = *(const f4_t*)(xin + (size_t)(r0 + row) * D + lane4);
    xv[0] = clipf(xv[0]); xv[1] = clipf(xv[1]); xv[2] = clipf(xv[2]); xv[3] = clipf(xv[3]);
    *(f4_t*)&xrow[wid * 256 + lane4] = xv;
    __builtin_amdgcn_wave_barrier();
    if (lane < 16) {   // numpy pairwise sum of x^2 (exact order)
      const int hf = lane >> 3, jj = lane & 7;
      const float* base = &xrow[wid * 256 + hf * 128 + jj];
      float v = base[0];
      float rs = v * v;
      #pragma unroll
      for (int m = 1; m < 16; ++m) { v = base[8 * m]; rs += v * v; }
      rpart[wid * 16 + lane] = rs;
    }
    __builtin_amdgcn_wave_barrier();
    float p[16];
    #pragma unroll
    for (int j = 0; j < 16; ++j) p[j] = rpart[wid * 16 + j];
    float h0 = ((p[0] + p[1]) + (p[2] + p[3])) + ((p[4] + p[5]) + (p[6] + p[7]));
    float h1 = ((p[8] + p[9]) + (p[10] + p[11])) + ((p[12] + p[13]) + (p[14] + p[15]));
    float sx = h0 + h1;

    int nc = cnt[row]; nc = nc > CAP ? CAP : nc;
    float bd = INFINITY; int bk = 0;
    for (int ci = 0; ci < nc; ++ci) {
      int k = cand[row][ci];
      f4_t ev = *(const f4_t*)(emb + (size_t)k * D + lane4);
      double dd = (double)xv[0] * (double)ev[0] + (double)xv[1] * (double)ev[1]
                + (double)xv[2] * (double)ev[2] + (double)xv[3] * (double)ev[3];
      #pragma unroll
      for (int off = 1; off < 64; off <<= 1) dd += __shfl_xor(dd, off, 64);
      float T1 = sx + senp[k];          // fp32, numpy op order
      float T2 = (float)(2.0 * dd);     // fp32-rounded 2*dot
      float d  = T1 - T2;               // final fp32 quantization like numpy
      if (d < bd || (d == bd && k < bk)) { bd = d; bk = k; }
    }

    f4_t ev = *(const f4_t*)(emb + (size_t)bk * D + lane4);
    *(f4_t*)(out + (size_t)(r0 + row) * D + lane4) = ev;
    float ls = 0.0f;
    #pragma unroll
    for (int i = 0; i < 4; ++i) { float df = ev[i] - xv[i]; ls += df * df; }
    #pragma unroll
    for (int off = 1; off < 64; off <<= 1) ls += __shfl_xor(ls, off, 64);
    if (lane == 0) atomicAdd(&blksum, ls);
  }
  __syncthreads();
  if (tid == 0) atomicAdd(lossacc, blksum);
}

// ---------------- finalize loss ----------------
__global__ void vq_fin(const float* __restrict__ lossacc, float* __restrict__ out) {
  out[NOUT] = 1.25f * lossacc[0] / 8388608.0f;
}

extern "C" void kernel_launch(void* const* d_in, const int* in_sizes, int n_in,
                              void* d_out, int out_size, void* d_ws, size_t ws_size,
                              hipStream_t stream) {
  const float* xin = (const float*)d_in[0];
  const float* emb = (const float*)d_in[1];
  float* out = (float*)d_out;
  _Float16* femb = (_Float16*)d_ws;                 // 4 MB, 16B-aligned at base
  float* wsf     = (float*)d_ws;
  float* senp    = wsf + 1048576;                   // 8192 floats
  float* ekkb    = senp + KCODES;                   // 8192 floats
  float* lossacc = ekkb + KCODES;                   // 1 float
  vq_setup<<<dim3(KCODES / 4), dim3(256), 0, stream>>>(emb, senp, ekkb, lossacc);
  vq_pack<<<dim3(NTILES), dim3(256), 0, stream>>>(emb, femb);
  vq_main<<<dim3(NROWS / MB), dim3(THREADS), 0, stream>>>(xin, femb, emb, senp, ekkb, out, lossacc);
  vq_fin<<<dim3(1), dim3(1), 0, stream>>>(lossacc, out);
}

// Round 3
// 354.405 us; speedup vs baseline: 2.3182x; 1.0637x over previous
//
#include <hip/hip_runtime.h>

// VectorQuantizer on MI355X — R3.
// R2 post-mortem: per-iter global ekkb load serialized the DMA pipeline (in-order vmcnt:
// waiting on the ekk value == s_waitcnt vmcnt(0) == draining the 32KB tile DMA each iter).
// R3: ekk table LDS-resident (ds_read, lgkm-only), subtract moved to filter stage -> the
// compute phase has no vector-memory ops; DMA overlaps fully. Also fuses setup into pack.

#define D        256
#define KCODES   8192
#define NROWS    32768
#define MB       128      // rows per block
#define NT       64       // codes per tile
#define NTILES   (KCODES / NT)   // 128
#define THREADS  512
#define CAP      32
#define MARGIN   0.03f    // filter margin (f16 score err RMS ~1e-3, bound ~7e-3)
#define BIAS     32.0f    // shift scores positive so int-compare == float-compare
#define NOUT     8388608

typedef _Float16 h8_t __attribute__((ext_vector_type(8)));
typedef float    f4_t __attribute__((ext_vector_type(4)));

__device__ __forceinline__ float clipf(float v) { return fminf(1.0f, fmaxf(-1.0f, v)); }

// max across each 16-lane group via row_ror DPP
#define DPP_ROR(x, n) __int_as_float(__builtin_amdgcn_update_dpp( \
    0, __float_as_int(x), 0x120 + (n), 0xF, 0xF, true))
__device__ __forceinline__ float maxrow16(float x) {
  x = fmaxf(x, DPP_ROR(x, 1));
  x = fmaxf(x, DPP_ROR(x, 2));
  x = fmaxf(x, DPP_ROR(x, 4));
  x = fmaxf(x, DPP_ROR(x, 8));
  return x;
}

__device__ __forceinline__ void gld_lds16(const void* g, void* l) {
  __builtin_amdgcn_global_load_lds(
      (const __attribute__((address_space(1))) unsigned int*)g,
      (__attribute__((address_space(3))) unsigned int*)l, 16, 0, 0);
}

// ---------------- pack f16 codebook (fragment-major, DMA-linear) + numpy-order sum(e^2) ----
// tile t (64 codes): 16B chunk c in [0,2048): kc=c>>8, g=(c>>6)&3, lane=c&63;
// content = emb16[t*64 + g*16 + (lane&15)][kc*32 + (lane>>4)*8 .. +8]
__global__ void vq_packsetup(const float* __restrict__ emb, _Float16* __restrict__ femb,
                             float* __restrict__ senp, float* __restrict__ ekkb,
                             float* __restrict__ lossacc) {
  const int t = blockIdx.x;
  if (t == 0 && threadIdx.x == 0) lossacc[0] = 0.0f;
  #pragma unroll
  for (int j = 0; j < 8; ++j) {
    int c = j * 256 + threadIdx.x;
    int kc = c >> 8, g = (c >> 6) & 3, ln = c & 63;
    int code = t * 64 + g * 16 + (ln & 15);
    int k0 = kc * 32 + (ln >> 4) * 8;
    const float* sp = emb + (size_t)code * D + k0;
    f4_t v0 = *(const f4_t*)sp, v1 = *(const f4_t*)(sp + 4);
    h8_t h;
    h[0] = (_Float16)v0[0]; h[1] = (_Float16)v0[1];
    h[2] = (_Float16)v0[2]; h[3] = (_Float16)v0[3];
    h[4] = (_Float16)v1[0]; h[5] = (_Float16)v1[1];
    h[6] = (_Float16)v1[2]; h[7] = (_Float16)v1[3];
    *(h8_t*)(femb + (size_t)t * 16384 + (size_t)c * 8) = h;
  }
  // setup: sum(e^2) in numpy pairwise order; butterfly == same binary tree (commutative only)
  const int lane = threadIdx.x & 63;
  const int w    = threadIdx.x >> 6;
  const int jdx  = lane & 15, hf = jdx >> 3, jj = jdx & 7;
  #pragma unroll
  for (int cc = 0; cc < 4; ++cc) {
    int k = t * 64 + w * 16 + cc * 4 + (lane >> 4);
    const float* base = emb + (size_t)k * D + hf * 128 + jj;
    float v = base[0];
    float r = v * v;
    #pragma unroll
    for (int m = 1; m < 16; ++m) { v = base[8 * m]; r += v * v; }
    r += __shfl_xor(r, 1, 64);
    r += __shfl_xor(r, 2, 64);
    r += __shfl_xor(r, 4, 64);
    r += __shfl_xor(r, 8, 64);
    if (jdx == 0) { senp[k] = r; ekkb[k] = 0.5f * r - BIAS; }
  }
}

// ---------------- main ----------------
__global__ void __launch_bounds__(THREADS, 2)
vq_main(const float* __restrict__ xin, const _Float16* __restrict__ femb,
        const float* __restrict__ emb, const float* __restrict__ senp,
        const float* __restrict__ ekkb, float* __restrict__ out,
        float* __restrict__ lossacc) {
  __shared__ alignas(16) char Bs0[32768];
  __shared__ alignas(16) char Bs1[32768];
  __shared__ float Eks[KCODES];              // 32 KB: 0.5*||e||^2 - BIAS, LDS-resident
  __shared__ int rowmaxI[MB];
  __shared__ int cnt[MB];
  __shared__ unsigned short cand[MB][CAP];
  __shared__ float blksum;

  const int tid  = threadIdx.x;
  const int lane = tid & 63;
  const int wid  = tid >> 6;
  const int l15  = lane & 15;
  const int quad = lane >> 4;
  const int mw   = wid >> 2;   // 0..1 : 64-row group
  const int ng   = wid & 3;    // 0..3 : 16-col group
  const int r0   = blockIdx.x * MB;

  for (int i = tid; i < MB; i += THREADS) { rowmaxI[i] = 0; cnt[i] = 0; }
  if (tid == 0) blksum = 0.0f;

  // ---- stage ekk table into LDS (one-time; lgkm-only access thereafter)
  #pragma unroll
  for (int i = 0; i < 4; ++i) {
    int e = (i * THREADS + tid) * 4;
    *(f4_t*)&Eks[e] = *(const f4_t*)&ekkb[e];
  }

  // ---- stage x-tile (clipped f16, fragment order) into Bs0 (rows 0..63) / Bs1 (64..127)
  #pragma unroll
  for (int j = 0; j < 8; ++j) {
    int c = j * THREADS + tid;            // 0..4095
    int half = c >> 11;
    int c2 = c & 2047;
    int kc = c2 >> 8, g = (c2 >> 6) & 3, ln = c2 & 63;
    int row = half * 64 + g * 16 + (ln & 15);
    int k0 = kc * 32 + (ln >> 4) * 8;
    const float* ap = xin + (size_t)(r0 + row) * D + k0;
    f4_t v0 = *(const f4_t*)ap, v1 = *(const f4_t*)(ap + 4);
    h8_t h;
    h[0] = (_Float16)clipf(v0[0]); h[1] = (_Float16)clipf(v0[1]);
    h[2] = (_Float16)clipf(v0[2]); h[3] = (_Float16)clipf(v0[3]);
    h[4] = (_Float16)clipf(v1[0]); h[5] = (_Float16)clipf(v1[1]);
    h[6] = (_Float16)clipf(v1[2]); h[7] = (_Float16)clipf(v1[3]);
    *(h8_t*)((half ? Bs1 : Bs0) + (size_t)c2 * 16) = h;
  }
  __syncthreads();

  // ---- A fragments -> registers (whole K-loop invariant), 64 VGPRs x2 halves
  h8_t afrag[4][8];
  {
    const char* abase = mw ? Bs1 : Bs0;
    #pragma unroll
    for (int ms = 0; ms < 4; ++ms)
      #pragma unroll
      for (int kc = 0; kc < 8; ++kc)
        afrag[ms][kc] = *(const h8_t*)(abase + (kc * 4 + ms) * 1024 + lane * 16);
  }
  __syncthreads();   // reads done before DMA overwrites Bs0

  const char* gth = (const char*)femb + (size_t)(wid * 1024 + lane * 16);
  #pragma unroll
  for (int q = 0; q < 4; ++q)   // prefetch tile 0 -> Bs0
    gld_lds16(gth + q * 8192, Bs0 + (q * 8 + wid) * 1024);

  float Lbm[4][4];
  #pragma unroll
  for (int a = 0; a < 4; ++a)
    #pragma unroll
    for (int b = 0; b < 4; ++b) Lbm[a][b] = -1e30f;

  const int mycol = ng * 16 + l15;

  for (int t = 0; t < NTILES; ++t) {
    char* cur = (t & 1) ? Bs1 : Bs0;
    char* nxt = (t & 1) ? Bs0 : Bs1;
    __syncthreads();            // DMA(t) drained; prior reads of nxt finished
    if (t + 1 < NTILES) {
      const char* g2 = gth + (size_t)(t + 1) * 32768;
      #pragma unroll
      for (int q = 0; q < 4; ++q)
        gld_lds16(g2 + q * 8192, nxt + (q * 8 + wid) * 1024);
    }
    const int c0 = t * NT;
    float ekk = Eks[c0 + mycol];     // ds_read_b32: lgkm-only, no vmcnt interaction
    f4_t acc[4];
    #pragma unroll
    for (int ms = 0; ms < 4; ++ms) { f4_t z = {0.f, 0.f, 0.f, 0.f}; acc[ms] = z; }
    #pragma unroll
    for (int kc = 0; kc < 8; ++kc) {
      h8_t b = *(const h8_t*)(cur + (kc * 4 + ng) * 1024 + lane * 16);
      #pragma unroll
      for (int ms = 0; ms < 4; ++ms)
        acc[ms] = __builtin_amdgcn_mfma_f32_16x16x32_f16(afrag[ms][kc], b, acc[ms], 0, 0, 0);
    }
    // margin filter, register-gated (Lbm <= global rowmax - MARGIN, monotone)
    #pragma unroll
    for (int ms = 0; ms < 4; ++ms) {
      #pragma unroll
      for (int r = 0; r < 4; ++r) {
        float t0 = acc[ms][r] - ekk;
        if (__any(t0 > Lbm[ms][r])) {
          int row = mw * 64 + ms * 16 + quad * 4 + r;
          float mm = maxrow16(t0);
          if (l15 == 0) atomicMax(&rowmaxI[row], __float_as_int(mm));
          float cut = __int_as_float(rowmaxI[row]) - MARGIN;
          Lbm[ms][r] = cut;
          if (t0 >= cut) {
            int s = atomicAdd(&cnt[row], 1);
            if (s < CAP) cand[row][s] = (unsigned short)(c0 + mycol);
          }
        }
      }
    }
  }
  __syncthreads();

  // ---------------- exact rescore + output + loss (scratch over Bs0) ----------------
  float* xrow  = (float*)Bs0;           // 8 waves x 256 floats = 8 KB
  float* rpart = (float*)(Bs0 + 8192);  // 8 waves x 16 floats
  const int lane4 = lane * 4;
  for (int rr = 0; rr < 16; ++rr) {
    const int row = wid + rr * 8;
    f4_t xv = *(const f4_t*)(xin + (size_t)(r0 + row) * D + lane4);
    xv[0] = clipf(xv[0]); xv[1] = clipf(xv[1]); xv[2] = clipf(xv[2]); xv[3] = clipf(xv[3]);
    *(f4_t*)&xrow[wid * 256 + lane4] = xv;
    __builtin_amdgcn_wave_barrier();
    if (lane < 16) {   // numpy pairwise sum of x^2 (exact order)
      const int hf = lane >> 3, jj = lane & 7;
      const float* base = &xrow[wid * 256 + hf * 128 + jj];
      float v = base[0];
      float rs = v * v;
      #pragma unroll
      for (int m = 1; m < 16; ++m) { v = base[8 * m]; rs += v * v; }
      rpart[wid * 16 + lane] = rs;
    }
    __builtin_amdgcn_wave_barrier();
    float p[16];
    #pragma unroll
    for (int j = 0; j < 16; ++j) p[j] = rpart[wid * 16 + j];
    float h0 = ((p[0] + p[1]) + (p[2] + p[3])) + ((p[4] + p[5]) + (p[6] + p[7]));
    float h1 = ((p[8] + p[9]) + (p[10] + p[11])) + ((p[12] + p[13]) + (p[14] + p[15]));
    float sx = h0 + h1;

    int nc = cnt[row]; nc = nc > CAP ? CAP : nc;
    float bd = INFINITY; int bk = 0;
    for (int ci = 0; ci < nc; ++ci) {
      int k = cand[row][ci];
      f4_t ev = *(const f4_t*)(emb + (size_t)k * D + lane4);
      double dd = (double)xv[0] * (double)ev[0] + (double)xv[1] * (double)ev[1]
                + (double)xv[2] * (double)ev[2] + (double)xv[3] * (double)ev[3];
      #pragma unroll
      for (int off = 1; off < 64; off <<= 1) dd += __shfl_xor(dd, off, 64);
      float T1 = sx + senp[k];          // fp32, numpy op order
      float T2 = (float)(2.0 * dd);     // fp32-rounded 2*dot
      float d  = T1 - T2;               // final fp32 quantization like numpy
      if (d < bd || (d == bd && k < bk)) { bd = d; bk = k; }
    }

    f4_t ev = *(const f4_t*)(emb + (size_t)bk * D + lane4);
    *(f4_t*)(out + (size_t)(r0 + row) * D + lane4) = ev;
    float ls = 0.0f;
    #pragma unroll
    for (int i = 0; i < 4; ++i) { float df = ev[i] - xv[i]; ls += df * df; }
    #pragma unroll
    for (int off = 1; off < 64; off <<= 1) ls += __shfl_xor(ls, off, 64);
    if (lane == 0) atomicAdd(&blksum, ls);
  }
  __syncthreads();
  if (tid == 0) atomicAdd(lossacc, blksum);
}

// ---------------- finalize loss ----------------
__global__ void vq_fin(const float* __restrict__ lossacc, float* __restrict__ out) {
  out[NOUT] = 1.25f * lossacc[0] / 8388608.0f;
}

extern "C" void kernel_launch(void* const* d_in, const int* in_sizes, int n_in,
                              void* d_out, int out_size, void* d_ws, size_t ws_size,
                              hipStream_t stream) {
  const float* xin = (const float*)d_in[0];
  const float* emb = (const float*)d_in[1];
  float* out = (float*)d_out;
  _Float16* femb = (_Float16*)d_ws;                 // 4 MB, 16B-aligned at base
  float* wsf     = (float*)d_ws;
  float* senp    = wsf + 1048576;                   // 8192 floats
  float* ekkb    = senp + KCODES;                   // 8192 floats
  float* lossacc = ekkb + KCODES;                   // 1 float
  vq_packsetup<<<dim3(NTILES), dim3(256), 0, stream>>>(emb, femb, senp, ekkb, lossacc);
  vq_main<<<dim3(NROWS / MB), dim3(THREADS), 0, stream>>>(xin, femb, emb, senp, ekkb, out, lossacc);
  vq_fin<<<dim3(1), dim3(1), 0, stream>>>(lossacc, out);
}